// Round 6
// baseline (29010.779 us; speedup 1.0000x reference)
//
#include <hip/hip_runtime.h>

// ---------------------------------------------------------------------------
// WorldModelGRU (gfx950) — ROUND 6: fp32-OUTPUT hypothesis test.
// Established: inputs fp32 (r1 NaN), I/O geometry exact (r5 beacons silent),
// t>=1 logits irrelevant to the 1.0507 error (r5 zeroing no-op on absmax),
// three verified pipelines agree bit-exactly yet fail identically.
// Remaining untested assumption: output dtype. Harness doc says output is the
// REFERENCE's dtype (jnp.float32) -> float*. This round stores ALL outputs as
// fp32. PASS => dtype was the bug all along. NaN => output really bf16.
// Pipeline: round-4 fp32 VALU (correctness-first; optimize after pass).
// ---------------------------------------------------------------------------

#define BB 4096
#define HH 512
#define TT 16
#define LL 3

// ---------------------------------------------------------------------------
// VALU fused GRU cell (fp32). Grid (B/64, H/32), block 256.
// Thread (tx=tid&15, ty=tid>>4) computes rows ty*4+{0..3}, cols tx*2+{0,1}.
// acc0=r-pre, acc1=z-pre, acc2=i_n, acc3=h_n (sans bias; biases are zero but
// handled anyway).
// ---------------------------------------------------------------------------
__global__ __launch_bounds__(256) void v_gru_cell(
    const float* __restrict__ X,     // [B,H]
    const float* __restrict__ Hp,    // [B,H]
    const float* __restrict__ Wih,   // [3H,H]
    const float* __restrict__ Whh,   // [3H,H]
    const float* __restrict__ bih,   // [3H]
    const float* __restrict__ bhh,   // [3H]
    float* __restrict__ Hout)        // [B,H]
{
    const int rowBase = blockIdx.x * 64;
    const int colBase = blockIdx.y * 32;
    const int tid = threadIdx.x;
    const int tx = tid & 15;
    const int ty = tid >> 4;

    __shared__ float Xs[64][17];
    __shared__ float Hs[64][17];
    __shared__ float Ws[6][32][17];

    float acc[4][4][2];
    #pragma unroll
    for (int g = 0; g < 4; g++)
        #pragma unroll
        for (int r = 0; r < 4; r++)
            acc[g][r][0] = acc[g][r][1] = 0.f;

    for (int k0 = 0; k0 < HH; k0 += 16) {
        {
            int row = tid >> 2;
            int kb  = (tid & 3) * 4;
            const float4 vx = *(const float4*)(X  + (size_t)(rowBase + row) * HH + k0 + kb);
            const float4 vh = *(const float4*)(Hp + (size_t)(rowBase + row) * HH + k0 + kb);
            Xs[row][kb + 0] = vx.x; Xs[row][kb + 1] = vx.y;
            Xs[row][kb + 2] = vx.z; Xs[row][kb + 3] = vx.w;
            Hs[row][kb + 0] = vh.x; Hs[row][kb + 1] = vh.y;
            Hs[row][kb + 2] = vh.z; Hs[row][kb + 3] = vh.w;
        }
        {
            int wrow = tid >> 3;
            int wk   = (tid & 7) * 2;
            #pragma unroll
            for (int i = 0; i < 6; i++) {
                const float* src = (i < 3) ? Wih : Whh;
                int g = (i < 3) ? i : (i - 3);
                const float2 w = *(const float2*)(
                    src + (size_t)(g * HH + colBase + wrow) * HH + k0 + wk);
                Ws[i][wrow][wk]     = w.x;
                Ws[i][wrow][wk + 1] = w.y;
            }
        }
        __syncthreads();

        #pragma unroll
        for (int k = 0; k < 16; k++) {
            float xr[4], hr[4];
            #pragma unroll
            for (int r = 0; r < 4; r++) {
                xr[r] = Xs[ty * 4 + r][k];
                hr[r] = Hs[ty * 4 + r][k];
            }
            #pragma unroll
            for (int c = 0; c < 2; c++) {
                int wcol = tx * 2 + c;
                float wr = Ws[0][wcol][k], wz = Ws[1][wcol][k], wn = Ws[2][wcol][k];
                float vr = Ws[3][wcol][k], vz = Ws[4][wcol][k], vn = Ws[5][wcol][k];
                #pragma unroll
                for (int r = 0; r < 4; r++) {
                    acc[0][r][c] += xr[r] * wr + hr[r] * vr;
                    acc[1][r][c] += xr[r] * wz + hr[r] * vz;
                    acc[2][r][c] += xr[r] * wn;
                    acc[3][r][c] += hr[r] * vn;
                }
            }
        }
        __syncthreads();
    }

    #pragma unroll
    for (int c = 0; c < 2; c++) {
        int j = colBase + tx * 2 + c;
        float br = bih[j] + bhh[j];
        float bz = bih[HH + j] + bhh[HH + j];
        float bni = bih[2 * HH + j];
        float bnh = bhh[2 * HH + j];
        #pragma unroll
        for (int r = 0; r < 4; r++) {
            int b = rowBase + ty * 4 + r;
            float rr = 1.f / (1.f + __expf(-(acc[0][r][c] + br)));
            float z  = 1.f / (1.f + __expf(-(acc[1][r][c] + bz)));
            float n  = tanhf(acc[2][r][c] + bni + rr * (acc[3][r][c] + bnh));
            Hout[(size_t)b * HH + j] = (1.f - z) * n + z * Hp[(size_t)b * HH + j];
        }
    }
}

// ---------------------------------------------------------------------------
// VALU GEMM (fp32): out[b*rstride + j] = sum_k A[arow(b),k]*W[j,k] + bias[j]
// Optional gather: arow = gt[b*16 + t_fixed]. Output fp32, row stride rstride.
// ---------------------------------------------------------------------------
__global__ __launch_bounds__(256) void v_gemm(
    const float* __restrict__ A,
    const int* __restrict__ gt, int t_fixed,
    const float* __restrict__ W,
    const float* __restrict__ bias,
    float* __restrict__ out, long rstride)
{
    const int rowBase = blockIdx.x * 64;
    const int colBase = blockIdx.y * 64;
    const int tid = threadIdx.x;
    const int tx = tid & 15;
    const int ty = tid >> 4;

    __shared__ float As[64][17];
    __shared__ float Bs[64][17];

    float acc[4][4];
    #pragma unroll
    for (int r = 0; r < 4; r++)
        #pragma unroll
        for (int c = 0; c < 4; c++)
            acc[r][c] = 0.f;

    for (int k0 = 0; k0 < HH; k0 += 16) {
        int row = tid >> 2;
        int kb  = (tid & 3) * 4;
        int rg = rowBase + row;
        long arow = gt ? (long)gt[(size_t)rg * TT + t_fixed] : (long)rg;
        const float4 va = *(const float4*)(A + (size_t)arow * HH + k0 + kb);
        const float4 vw = *(const float4*)(W + (size_t)(colBase + row) * HH + k0 + kb);
        As[row][kb + 0] = va.x; As[row][kb + 1] = va.y;
        As[row][kb + 2] = va.z; As[row][kb + 3] = va.w;
        Bs[row][kb + 0] = vw.x; Bs[row][kb + 1] = vw.y;
        Bs[row][kb + 2] = vw.z; Bs[row][kb + 3] = vw.w;
        __syncthreads();

        #pragma unroll
        for (int k = 0; k < 16; k++) {
            float a[4], w[4];
            #pragma unroll
            for (int r = 0; r < 4; r++) a[r] = As[ty * 4 + r][k];
            #pragma unroll
            for (int c = 0; c < 4; c++) w[c] = Bs[tx * 4 + c][k];
            #pragma unroll
            for (int r = 0; r < 4; r++)
                #pragma unroll
                for (int c = 0; c < 4; c++)
                    acc[r][c] += a[r] * w[c];
        }
        __syncthreads();
    }

    #pragma unroll
    for (int r = 0; r < 4; r++) {
        int b = rowBase + ty * 4 + r;
        #pragma unroll
        for (int c = 0; c < 4; c++) {
            int j = colBase + tx * 4 + c;
            out[(long)b * rstride + j] = acc[r][c] + bias[j];
        }
    }
}

// x0 = action @ W_a^T + b_a (K=3), fp32
__global__ void k_x0(const float* __restrict__ action,
                     const float* __restrict__ W_a,
                     const float* __restrict__ b_a,
                     float* __restrict__ x0)
{
    int idx = blockIdx.x * 256 + threadIdx.x;
    int b = idx >> 9;
    int h = idx & 511;
    x0[idx] = action[b * 3 + 0] * W_a[h * 3 + 0] +
              action[b * 3 + 1] * W_a[h * 3 + 1] +
              action[b * 3 + 2] * W_a[h * 3 + 2] + b_a[h];
}

// reward / done heads: one wave per batch row, fp32 out
__global__ void k_heads(const float* __restrict__ h3,
                        const float* __restrict__ Wr, const float* __restrict__ br,
                        const float* __restrict__ Wd, const float* __restrict__ bd,
                        float* __restrict__ out_r,
                        float* __restrict__ out_d)
{
    int wave = threadIdx.x >> 6;
    int lane = threadIdx.x & 63;
    int b = blockIdx.x * 4 + wave;
    const float4 h0 = *(const float4*)(h3 + (size_t)b * HH + lane * 8);
    const float4 h1 = *(const float4*)(h3 + (size_t)b * HH + lane * 8 + 4);
    const float4 wr0 = *(const float4*)(Wr + lane * 8);
    const float4 wr1 = *(const float4*)(Wr + lane * 8 + 4);
    const float4 wd0 = *(const float4*)(Wd + lane * 8);
    const float4 wd1 = *(const float4*)(Wd + lane * 8 + 4);
    float sr = h0.x * wr0.x + h0.y * wr0.y + h0.z * wr0.z + h0.w * wr0.w +
               h1.x * wr1.x + h1.y * wr1.y + h1.z * wr1.z + h1.w * wr1.w;
    float sd = h0.x * wd0.x + h0.y * wd0.y + h0.z * wd0.z + h0.w * wd0.w +
               h1.x * wd1.x + h1.y * wd1.y + h1.z * wd1.z + h1.w * wd1.w;
    #pragma unroll
    for (int off = 32; off > 0; off >>= 1) {
        sr += __shfl_xor(sr, off, 64);
        sd += __shfl_xor(sd, off, 64);
    }
    if (lane == 0) {
        out_r[b] = sr + br[0];
        out_d[b] = sd + bd[0];
    }
}

// ---------------------------------------------------------------------------
extern "C" void kernel_launch(void* const* d_in, const int* in_sizes, int n_in,
                              void* d_out, int out_size, void* d_ws, size_t ws_size,
                              hipStream_t stream)
{
    const float* action      = (const float*)d_in[0];
    const float* prev_hidden = (const float*)d_in[1];
    const int*   gt          = (const int*)d_in[2];
    const float* W_a   = (const float*)d_in[3];
    const float* b_a   = (const float*)d_in[4];
    const float* emb   = (const float*)d_in[5];
    const float* W_tp  = (const float*)d_in[6];
    const float* b_tp  = (const float*)d_in[7];
    const float* W_ih  = (const float*)d_in[8];
    const float* W_hh  = (const float*)d_in[9];
    const float* b_ih  = (const float*)d_in[10];
    const float* b_hh  = (const float*)d_in[11];
    const float* W_out = (const float*)d_in[12];
    const float* b_out = (const float*)d_in[13];
    const float* W_r   = (const float*)d_in[14];
    const float* b_r   = (const float*)d_in[15];
    const float* W_d   = (const float*)d_in[16];
    const float* b_d   = (const float*)d_in[17];

    const size_t BH = (size_t)BB * HH;   // 2,097,152

    // ---- fp32 OUTPUT layout (hypothesis under test) ----
    float* of        = (float*)d_out;
    float* o_logits  = of;                              // B*T*C = 33,554,432
    float* o_rew     = of + (size_t)BB * TT * 512;      // B
    float* o_done    = o_rew + BB;                      // B
    float* o_fh      = o_done + BB;                     // L*B*H = 6,291,456

    // fp32 workspace: 9*BH floats = 75.5 MB (verified fits in round 5)
    float* wsf  = (float*)d_ws;
    float* x0   = wsf;
    float* tok0 = x0 + BH;
    float* tok1 = tok0 + BH;
    float* hA   = tok1 + BH;
    float* hB   = hA + (size_t)LL * BH;

    k_x0<<<(BB * HH) / 256, 256, 0, stream>>>(action, W_a, b_a, x0);
    hipMemsetAsync(tok1, 0, BH * sizeof(float), stream);

    float* bufs[2] = { hA, hB };
    float* toks[2] = { tok0, tok1 };

    for (int s = 0; s <= 16; s++) {
        // token-embedding input for this step (s>=2): proj(emb[gt[:, s-2]])
        if (s >= 2) {
            v_gemm<<<dim3(BB / 64, 8), 256, 0, stream>>>(
                emb, gt, s - 2, W_tp, b_tp, toks[s & 1], (long)HH);
        }
        const float* src = (s == 0) ? prev_hidden : bufs[(s + 1) & 1];
        float* dst = bufs[s & 1];
        for (int l = 0; l < LL; l++) {
            const float* X =
                (l == 0) ? ((s == 0) ? x0 : toks[s & 1])
                         : dst + (size_t)(l - 1) * BH;
            v_gru_cell<<<dim3(BB / 64, HH / 32), 256, 0, stream>>>(
                X, src + (size_t)l * BH,
                W_ih + (size_t)l * 3 * HH * HH, W_hh + (size_t)l * 3 * HH * HH,
                b_ih + (size_t)l * 3 * HH, b_hh + (size_t)l * 3 * HH,
                dst + (size_t)l * BH);
        }
        if (s == 0) {
            k_heads<<<BB / 4, 256, 0, stream>>>(dst + 2 * BH, W_r, b_r, W_d, b_d,
                                                o_rew, o_done);
        } else {
            // logits for token t=s-1 -> out[b, t, :]  ([B,T,C] fp32)
            v_gemm<<<dim3(BB / 64, 8), 256, 0, stream>>>(
                dst + 2 * BH, nullptr, 0, W_out, b_out,
                o_logits + (size_t)(s - 1) * 512, (long)TT * 512);
        }
    }

    // final hidden stack (after s=16, dst = bufs[0] = hA) -> fp32 output
    hipMemcpyAsync(o_fh, hA, (size_t)LL * BH * sizeof(float),
                   hipMemcpyDeviceToDevice, stream);
}